// Round 1
// baseline (239.321 us; speedup 1.0000x reference)
//
#include <hip/hip_runtime.h>
#include <cstdint>
#include <cstddef>

#define BATCH 8192
#define DIN   1025
#define HID   1024
#define NACT  1026
#define NHEAD 513
#define KSEL  32
#define KP0   1056   /* DIN padded to multiple of 32 */
#define NP2   1152   /* NACT padded to multiple of 128 */

typedef unsigned short u16;
typedef short bf16x8 __attribute__((ext_vector_type(8)));
typedef float f32x4 __attribute__((ext_vector_type(4)));

__device__ __forceinline__ u16 f2bf(float f) {
  unsigned u = __float_as_uint(f);
  u += 0x7fff + ((u >> 16) & 1);   // round-to-nearest-even
  return (u16)(u >> 16);
}

__device__ __forceinline__ void async_cp16(const u16* g, u16* l) {
  __builtin_amdgcn_global_load_lds((const __attribute__((address_space(1))) void*)g,
                                   (__attribute__((address_space(3))) void*)l,
                                   16, 0, 0);
}

// ---------------- conversion kernels ----------------

// state f32 [BATCH][DIN] -> bf16 [BATCH][KP0], zero-padded K
__global__ void cvt_state(const float* __restrict__ in, u16* __restrict__ out) {
  int k = blockIdx.x * 256 + threadIdx.x;
  int r = blockIdx.y;
  if (k >= KP0) return;
  float v = (k < DIN) ? in[(size_t)r * DIN + k] : 0.f;
  out[(size_t)r * KP0 + k] = f2bf(v);
}

// W f32 [K][N] -> Wt bf16 [Np][Kp] (transposed, zero-padded)
__global__ void cvt_w_t(const float* __restrict__ W, u16* __restrict__ Wt,
                        int K, int N, int Kp, int Np) {
  __shared__ float tile[32][33];
  int k0 = blockIdx.y * 32, n0 = blockIdx.x * 32;
  int tx = threadIdx.x, ty = threadIdx.y;
#pragma unroll
  for (int i = 0; i < 32; i += 8) {
    int k = k0 + ty + i, n = n0 + tx;
    tile[ty + i][tx] = (k < K && n < N) ? W[(size_t)k * N + n] : 0.f;
  }
  __syncthreads();
#pragma unroll
  for (int i = 0; i < 32; i += 8) {
    int n = n0 + ty + i, k = k0 + tx;
    if (n < Np && k < Kp) Wt[(size_t)n * Kp + k] = f2bf(tile[tx][ty + i]);
  }
}

// ---------------- GEMM: C[M][ldc] = A[M][K] * Bt[ldc][K]^T (+bias, relu) ----------------
// M=8192 always, tiles 128x128, BK=32, 4 waves of 64x64 (4x4 MFMA 16x16x32 tiles).

template<bool RELU, bool OBF16>
__global__ __launch_bounds__(256, 2)
void gemm_bt(const u16* __restrict__ A, const u16* __restrict__ Bt,
             const float* __restrict__ bias, int nbias,
             void* __restrict__ Cout, int ldc, int K)
{
  __shared__ __align__(16) u16 lds[8192];   // ldsA[128][32] | ldsB[128][32]
  u16* ldsA = lds;
  u16* ldsB = lds + 4096;

  const int tid   = threadIdx.x;
  const int wave  = tid >> 6;
  const int lane  = tid & 63;
  const int waveM = wave >> 1, waveN = wave & 1;
  const int lr = lane & 15, lq = lane >> 4;
  const size_t bm = (size_t)blockIdx.y * 128;
  const size_t bn = (size_t)blockIdx.x * 128;

  // staging: 512 chunks of 16B per tile; chunk c -> row c>>2, kquad c&3
  const int c0 = wave * 128 + lane;
  const int c1 = c0 + 64;
  const u16* gA0 = A  + (bm + (size_t)(c0 >> 2)) * K + (c0 & 3) * 8;
  const u16* gA1 = A  + (bm + (size_t)(c1 >> 2)) * K + (c1 & 3) * 8;
  const u16* gB0 = Bt + (bn + (size_t)(c0 >> 2)) * K + (c0 & 3) * 8;
  const u16* gB1 = Bt + (bn + (size_t)(c1 >> 2)) * K + (c1 & 3) * 8;
  // LDS dst: wave-uniform base, HW adds lane*16B
  u16* lA0 = ldsA + wave * 1024;
  u16* lA1 = ldsA + wave * 1024 + 512;
  u16* lB0 = ldsB + wave * 1024;
  u16* lB1 = ldsB + wave * 1024 + 512;

  f32x4 acc[4][4] = {};

  const u16* pa = ldsA + (waveM * 64 + lr) * 32 + lq * 8;
  const u16* pb = ldsB + (waveN * 64 + lr) * 32 + lq * 8;

  for (int k0 = 0; k0 < K; k0 += 32) {
    async_cp16(gA0 + k0, lA0);
    async_cp16(gA1 + k0, lA1);
    async_cp16(gB0 + k0, lB0);
    async_cp16(gB1 + k0, lB1);
    __syncthreads();

    bf16x8 af[4], bf[4];
#pragma unroll
    for (int t = 0; t < 4; ++t) {
      af[t] = *(const bf16x8*)(pa + t * 512);   // +16 rows * 32
      bf[t] = *(const bf16x8*)(pb + t * 512);
    }
#pragma unroll
    for (int tm = 0; tm < 4; ++tm)
#pragma unroll
      for (int tn = 0; tn < 4; ++tn)
        acc[tm][tn] = __builtin_amdgcn_mfma_f32_16x16x32_bf16(af[tm], bf[tn], acc[tm][tn], 0, 0, 0);
    __syncthreads();
  }

  // epilogue: D row = (lane>>4)*4 + r, col = lane&15  (m89-verified layout)
#pragma unroll
  for (int tm = 0; tm < 4; ++tm) {
    size_t row = bm + waveM * 64 + tm * 16 + lq * 4;
#pragma unroll
    for (int tn = 0; tn < 4; ++tn) {
      int col = (int)bn + waveN * 64 + tn * 16 + lr;
      float bv = (col < nbias) ? bias[col] : 0.f;
#pragma unroll
      for (int r = 0; r < 4; ++r) {
        float v = acc[tm][tn][r] + bv;
        if (RELU) v = fmaxf(v, 0.f);
        if (OBF16) ((u16*)Cout)[(row + r) * ldc + col] = f2bf(v);
        else       ((float*)Cout)[(row + r) * ldc + col] = v;
      }
    }
  }
}

// ---------------- sampling without replacement ----------------
// one block (2 waves) per batch row: wave 0 -> group R (cols 0..512),
// wave 1 -> group S (cols 513..1025).
// Incremental form: e_i = exp(x_i - m); S = sum e; T = sum e*x.
// step t: logZ = m + log(S_t); ent += logZ - T_t/S_t; logp += x_idx - logZ;
// S_{t+1} = S_t - e_idx; T_{t+1} = T_t - e_idx*x_idx  -> prefix sums over lanes.

__global__ void sample_k(const float* __restrict__ logits,
                         const int* __restrict__ idxR, const int* __restrict__ lenR,
                         const int* __restrict__ idxS, const int* __restrict__ lenS,
                         float* __restrict__ out)
{
  const int row  = blockIdx.x;
  const int w    = threadIdx.x >> 6;
  const int lane = threadIdx.x & 63;
  const float* x = logits + (size_t)row * NP2 + w * NHEAD;
  const int* sidx = (w ? idxS : idxR) + (size_t)row * KSEL;
  const int slen  = (w ? lenS : lenR)[row];

  // max over 513
  float m = -3.4e38f;
  for (int i = lane; i < NHEAD; i += 64) m = fmaxf(m, x[i]);
#pragma unroll
  for (int d = 32; d; d >>= 1) m = fmaxf(m, __shfl_xor(m, d, 64));

  // S0, T0
  float S = 0.f, T = 0.f;
  for (int i = lane; i < NHEAD; i += 64) {
    float xi = x[i];
    float e = expf(xi - m);
    S += e; T += e * xi;
  }
#pragma unroll
  for (int d = 32; d; d >>= 1) { S += __shfl_xor(S, d, 64); T += __shfl_xor(T, d, 64); }

  // per-step values on lanes 0..31 (t = lane)
  float e = 0.f, ex = 0.f, xt = 0.f;
  int active = (lane < KSEL) && (lane < slen);
  int valid = 0;
  if (active) {
    int id = sidx[lane];
    if (id >= 0) {
      valid = 1;
      xt = x[id];
      e  = expf(xt - m);
      ex = e * xt;
    }
  }
  // exclusive prefix over lanes 0..31
  float pe = e, pex = ex;
#pragma unroll
  for (int d = 1; d < 32; d <<= 1) {
    float a = __shfl_up(pe, d, 64);
    float b = __shfl_up(pex, d, 64);
    if (lane >= d) { pe += a; pex += b; }
  }
  float lp = 0.f, en = 0.f;
  if (active) {
    float St = S - (pe - e);
    float Tt = T - (pex - ex);
    float logZ = m + logf(St);
    en = logZ - Tt / St;
    if (valid) lp = xt - logZ;
  }
#pragma unroll
  for (int d = 32; d; d >>= 1) { lp += __shfl_xor(lp, d, 64); en += __shfl_xor(en, d, 64); }

  __shared__ float sh[4];
  if (lane == 0) { sh[w * 2] = lp; sh[w * 2 + 1] = en; }
  __syncthreads();
  if (threadIdx.x == 0) {
    out[row]         = sh[0] + sh[2];
    out[BATCH + row] = sh[1] + sh[3];
  }
}

// ---------------- launch ----------------

extern "C" void kernel_launch(void* const* d_in, const int* in_sizes, int n_in,
                              void* d_out, int out_size, void* d_ws, size_t ws_size,
                              hipStream_t stream) {
  (void)in_sizes; (void)n_in; (void)out_size; (void)ws_size;
  const float* state = (const float*)d_in[0];
  const float* W0 = (const float*)d_in[1];
  const float* b0 = (const float*)d_in[2];
  const float* W1 = (const float*)d_in[3];
  const float* b1 = (const float*)d_in[4];
  const float* W2 = (const float*)d_in[5];
  const float* b2 = (const float*)d_in[6];
  const int* idxR = (const int*)d_in[7];
  const int* lenR = (const int*)d_in[8];
  const int* idxS = (const int*)d_in[9];
  const int* lenS = (const int*)d_in[10];
  float* out = (float*)d_out;

  char* ws = (char*)d_ws;
  size_t off = 0;
  auto alloc = [&](size_t bytes) -> char* {
    char* p = ws + off;
    off = (off + bytes + 255) & ~(size_t)255;
    return p;
  };
  u16* As     = (u16*)alloc((size_t)BATCH * KP0 * 2);   // 17.3 MB
  u16* W0t    = (u16*)alloc((size_t)HID * KP0 * 2);     //  2.2 MB
  u16* W1t    = (u16*)alloc((size_t)HID * HID * 2);     //  2.1 MB
  u16* W2t    = (u16*)alloc((size_t)NP2 * HID * 2);     //  2.4 MB
  u16* h1     = (u16*)alloc((size_t)BATCH * HID * 2);   // 16.8 MB
  float* lgts = (float*)alloc((size_t)BATCH * NP2 * 4); // 37.7 MB
  u16* h2 = As;   // As is dead after GEMM1; reuse for h2

  cvt_state<<<dim3((KP0 + 255) / 256, BATCH), 256, 0, stream>>>(state, As);
  cvt_w_t<<<dim3(HID / 32, (KP0 + 31) / 32), dim3(32, 8), 0, stream>>>(W0, W0t, DIN, HID, KP0, HID);
  cvt_w_t<<<dim3(HID / 32, HID / 32),        dim3(32, 8), 0, stream>>>(W1, W1t, HID, HID, HID, HID);
  cvt_w_t<<<dim3(NP2 / 32, HID / 32),        dim3(32, 8), 0, stream>>>(W2, W2t, HID, NACT, HID, NP2);

  gemm_bt<true,  true ><<<dim3(HID / 128, BATCH / 128), 256, 0, stream>>>(As, W0t, b0, HID,  h1,   HID, KP0);
  gemm_bt<true,  true ><<<dim3(HID / 128, BATCH / 128), 256, 0, stream>>>(h1, W1t, b1, HID,  h2,   HID, HID);
  gemm_bt<false, false><<<dim3(NP2 / 128, BATCH / 128), 256, 0, stream>>>(h2, W2t, b2, NACT, lgts, NP2, HID);

  sample_k<<<BATCH, 128, 0, stream>>>(lgts, idxR, lenR, idxS, lenS, out);
}

// Round 2
// 220.860 us; speedup vs baseline: 1.0836x; 1.0836x over previous
//
#include <hip/hip_runtime.h>
#include <cstdint>
#include <cstddef>

#define BATCH 8192
#define DIN   1025
#define HID   1024
#define NACT  1026
#define NHEAD 513
#define KSEL  32
#define KP0   1088   /* DIN padded to multiple of 64 */
#define NP2   1152   /* NACT padded to multiple of 128 */

typedef unsigned short u16;
typedef short bf16x8 __attribute__((ext_vector_type(8)));
typedef float f32x4 __attribute__((ext_vector_type(4)));

__device__ __forceinline__ u16 f2bf(float f) {
  unsigned u = __float_as_uint(f);
  u += 0x7fff + ((u >> 16) & 1);   // round-to-nearest-even
  return (u16)(u >> 16);
}
__device__ __forceinline__ float bf2f(u16 h) {
  return __uint_as_float((unsigned)h << 16);
}

__device__ __forceinline__ void async_cp16(const u16* g, u16* l) {
  __builtin_amdgcn_global_load_lds((const __attribute__((address_space(1))) void*)g,
                                   (__attribute__((address_space(3))) void*)l,
                                   16, 0, 0);
}

// ---------------- conversion kernels ----------------

// state f32 [BATCH][DIN] -> bf16 [BATCH][KP0], zero-padded K
__global__ void cvt_state(const float* __restrict__ in, u16* __restrict__ out) {
  int k = blockIdx.x * 256 + threadIdx.x;
  int r = blockIdx.y;
  if (k >= KP0) return;
  float v = (k < DIN) ? in[(size_t)r * DIN + k] : 0.f;
  out[(size_t)r * KP0 + k] = f2bf(v);
}

// All three weight matrices: f32 [K][N] -> bf16 [Np][Kp] transposed+padded.
__global__ void cvt_w_all(const float* __restrict__ W0, const float* __restrict__ W1,
                          const float* __restrict__ W2,
                          u16* __restrict__ W0t, u16* __restrict__ W1t,
                          u16* __restrict__ W2t) {
  const float* W; u16* Wt; int K, N, Kp, Np;
  if (blockIdx.z == 0)      { W = W0; Wt = W0t; K = DIN; N = HID;  Kp = KP0; Np = HID; }
  else if (blockIdx.z == 1) { W = W1; Wt = W1t; K = HID; N = HID;  Kp = HID; Np = HID; }
  else                      { W = W2; Wt = W2t; K = HID; N = NACT; Kp = HID; Np = NP2; }
  int k0 = blockIdx.y * 32, n0 = blockIdx.x * 32;
  if (k0 >= Kp || n0 >= Np) return;
  __shared__ float tile[32][33];
  int tx = threadIdx.x, ty = threadIdx.y;
#pragma unroll
  for (int i = 0; i < 32; i += 8) {
    int k = k0 + ty + i, n = n0 + tx;
    tile[ty + i][tx] = (k < K && n < N) ? W[(size_t)k * N + n] : 0.f;
  }
  __syncthreads();
#pragma unroll
  for (int i = 0; i < 32; i += 8) {
    int n = n0 + ty + i, k = k0 + tx;
    if (n < Np && k < Kp) Wt[(size_t)n * Kp + k] = f2bf(tile[tx][ty + i]);
  }
}

// ---------------- GEMM: C[M][ldc] = A[M][K] * Bt[N][K]^T (+bias, relu) ----------------
// tiles 128x128, BK=64, 4 waves of 64x64 (4x4 MFMA 16x16x32 tiles).
// LDS layout per tile: 1024 chunks of 16B; chunk c holds (row=c>>3, kq=(c&7)^(row&7))
// -> XOR swizzle keeps the 128B-stride fragment reads at the 8-cycle bank floor
//    while the global_load_lds destination stays lane-contiguous.

template<bool RELU, bool OBF16>
__global__ __launch_bounds__(256, 2)
void gemm_bt(const u16* __restrict__ A, const u16* __restrict__ Bt,
             const float* __restrict__ bias, int nbias,
             void* __restrict__ Cout, int ldc, int K)
{
  __shared__ __align__(16) u16 lds[16384];   // ldsA[128][64] | ldsB[128][64] = 32 KB
  u16* ldsA = lds;
  u16* ldsB = lds + 8192;

  const int tid   = threadIdx.x;
  const int wave  = tid >> 6;
  const int lane  = tid & 63;
  const int waveM = wave >> 1, waveN = wave & 1;
  const int lr = lane & 15, lq = lane >> 4;
  const size_t bm = (size_t)blockIdx.y * 128;
  const size_t bn = (size_t)blockIdx.x * 128;

  // staging: thread covers chunks c_j = wave*64 + lane + j*256, j=0..3
  // row_j = baseRow + j*32 ; slot kq = lane&7 ; global kq g = (lane&7) ^ (lane>>3)
  const int baseRow = (wave * 64 + lane) >> 3;
  const int g = (lane & 7) ^ (lane >> 3);
  const u16* gA[4]; const u16* gB[4];
  u16 *lA[4], *lB[4];
#pragma unroll
  for (int j = 0; j < 4; ++j) {
    gA[j] = A  + (bm + baseRow + j * 32) * K + g * 8;
    gB[j] = Bt + (bn + baseRow + j * 32) * K + g * 8;
    lA[j] = ldsA + wave * 512 + j * 2048;   // wave-uniform; HW adds lane*16B
    lB[j] = ldsB + wave * 512 + j * 2048;
  }

  f32x4 acc[4][4] = {};

  // fragment read: element (row, kk + lq*8) at slot s = (lq + kk/8) ^ (row&7)
  const int r7 = lr & 7;
  const int s0 = lq ^ r7;         // kk = 0
  const int s1 = (lq + 4) ^ r7;   // kk = 32
  const u16* pa = ldsA + (waveM * 64 + lr) * 64;
  const u16* pb = ldsB + (waveN * 64 + lr) * 64;

  for (int k0 = 0; k0 < K; k0 += 64) {
#pragma unroll
    for (int j = 0; j < 4; ++j) {
      async_cp16(gA[j] + k0, lA[j]);
      async_cp16(gB[j] + k0, lB[j]);
    }
    __syncthreads();

#pragma unroll
    for (int kk = 0; kk < 2; ++kk) {
      const int s = kk ? s1 : s0;
      bf16x8 af[4], bf[4];
#pragma unroll
      for (int t = 0; t < 4; ++t) {
        af[t] = *(const bf16x8*)(pa + t * 1024 + s * 8);
        bf[t] = *(const bf16x8*)(pb + t * 1024 + s * 8);
      }
#pragma unroll
      for (int tm = 0; tm < 4; ++tm)
#pragma unroll
        for (int tn = 0; tn < 4; ++tn)
          acc[tm][tn] = __builtin_amdgcn_mfma_f32_16x16x32_bf16(af[tm], bf[tn], acc[tm][tn], 0, 0, 0);
    }
    __syncthreads();
  }

  // epilogue: D row = (lane>>4)*4 + r, col = lane&15  (m89-verified layout)
#pragma unroll
  for (int tm = 0; tm < 4; ++tm) {
    size_t row = bm + waveM * 64 + tm * 16 + lq * 4;
#pragma unroll
    for (int tn = 0; tn < 4; ++tn) {
      int col = (int)bn + waveN * 64 + tn * 16 + lr;
      float bv = (col < nbias) ? bias[col] : 0.f;
#pragma unroll
      for (int r = 0; r < 4; ++r) {
        float v = acc[tm][tn][r] + bv;
        if (RELU) v = fmaxf(v, 0.f);
        if (OBF16) ((u16*)Cout)[(row + r) * ldc + col] = f2bf(v);
        else       ((float*)Cout)[(row + r) * ldc + col] = v;
      }
    }
  }
}

// ---------------- sampling without replacement ----------------
// one block (2 waves) per batch row: wave 0 -> group R, wave 1 -> group S.
// Incremental: e_i = exp(x_i - m); S = sum e; T = sum e*x.
// step t: logZ = m + log(S_t); ent += logZ - T_t/S_t; logp += x_idx - logZ;
// removals via exclusive lane prefix sums over the 32 steps.

__global__ void sample_k(const u16* __restrict__ logits,
                         const int* __restrict__ idxR, const int* __restrict__ lenR,
                         const int* __restrict__ idxS, const int* __restrict__ lenS,
                         float* __restrict__ out)
{
  const int row  = blockIdx.x;
  const int w    = threadIdx.x >> 6;
  const int lane = threadIdx.x & 63;
  const u16* x = logits + (size_t)row * NP2 + w * NHEAD;
  const int* sidx = (w ? idxS : idxR) + (size_t)row * KSEL;
  const int slen  = (w ? lenS : lenR)[row];

  float m = -3.4e38f;
  for (int i = lane; i < NHEAD; i += 64) m = fmaxf(m, bf2f(x[i]));
#pragma unroll
  for (int d = 32; d; d >>= 1) m = fmaxf(m, __shfl_xor(m, d, 64));

  float S = 0.f, T = 0.f;
  for (int i = lane; i < NHEAD; i += 64) {
    float xi = bf2f(x[i]);
    float e = __expf(xi - m);
    S += e; T += e * xi;
  }
#pragma unroll
  for (int d = 32; d; d >>= 1) { S += __shfl_xor(S, d, 64); T += __shfl_xor(T, d, 64); }

  float e = 0.f, ex = 0.f, xt = 0.f;
  int active = (lane < KSEL) && (lane < slen);
  int valid = 0;
  if (active) {
    int id = sidx[lane];
    if (id >= 0) {
      valid = 1;
      xt = bf2f(x[id]);
      e  = __expf(xt - m);
      ex = e * xt;
    }
  }
  float pe = e, pex = ex;
#pragma unroll
  for (int d = 1; d < 32; d <<= 1) {
    float a = __shfl_up(pe, d, 64);
    float b = __shfl_up(pex, d, 64);
    if (lane >= d) { pe += a; pex += b; }
  }
  float lp = 0.f, en = 0.f;
  if (active) {
    float St = S - (pe - e);
    float Tt = T - (pex - ex);
    float logZ = m + __logf(St);
    en = logZ - Tt / St;
    if (valid) lp = xt - logZ;
  }
#pragma unroll
  for (int d = 32; d; d >>= 1) { lp += __shfl_xor(lp, d, 64); en += __shfl_xor(en, d, 64); }

  __shared__ float sh[4];
  if (lane == 0) { sh[w * 2] = lp; sh[w * 2 + 1] = en; }
  __syncthreads();
  if (threadIdx.x == 0) {
    out[row]         = sh[0] + sh[2];
    out[BATCH + row] = sh[1] + sh[3];
  }
}

// ---------------- launch ----------------

extern "C" void kernel_launch(void* const* d_in, const int* in_sizes, int n_in,
                              void* d_out, int out_size, void* d_ws, size_t ws_size,
                              hipStream_t stream) {
  (void)in_sizes; (void)n_in; (void)out_size; (void)ws_size;
  const float* state = (const float*)d_in[0];
  const float* W0 = (const float*)d_in[1];
  const float* b0 = (const float*)d_in[2];
  const float* W1 = (const float*)d_in[3];
  const float* b1 = (const float*)d_in[4];
  const float* W2 = (const float*)d_in[5];
  const float* b2 = (const float*)d_in[6];
  const int* idxR = (const int*)d_in[7];
  const int* lenR = (const int*)d_in[8];
  const int* idxS = (const int*)d_in[9];
  const int* lenS = (const int*)d_in[10];
  float* out = (float*)d_out;

  char* ws = (char*)d_ws;
  size_t off = 0;
  auto alloc = [&](size_t bytes) -> char* {
    char* p = ws + off;
    off = (off + bytes + 255) & ~(size_t)255;
    return p;
  };
  u16* As     = (u16*)alloc((size_t)BATCH * KP0 * 2);   // 17.8 MB
  u16* W0t    = (u16*)alloc((size_t)HID * KP0 * 2);     //  2.2 MB
  u16* W1t    = (u16*)alloc((size_t)HID * HID * 2);     //  2.1 MB
  u16* W2t    = (u16*)alloc((size_t)NP2 * HID * 2);     //  2.4 MB
  u16* h1     = (u16*)alloc((size_t)BATCH * HID * 2);   // 16.8 MB
  u16* lgts   = (u16*)alloc((size_t)BATCH * NP2 * 2);   // 18.9 MB
  u16* h2 = As;   // As is dead after GEMM1; reuse for h2

  cvt_state<<<dim3((KP0 + 255) / 256, BATCH), 256, 0, stream>>>(state, As);
  cvt_w_all<<<dim3(NP2 / 32, KP0 / 32, 3), dim3(32, 8), 0, stream>>>(W0, W1, W2, W0t, W1t, W2t);

  gemm_bt<true,  true><<<dim3(HID / 128, BATCH / 128), 256, 0, stream>>>(As, W0t, b0, HID,  h1,   HID, KP0);
  gemm_bt<true,  true><<<dim3(HID / 128, BATCH / 128), 256, 0, stream>>>(h1, W1t, b1, HID,  h2,   HID, HID);
  gemm_bt<false, true><<<dim3(NP2 / 128, BATCH / 128), 256, 0, stream>>>(h2, W2t, b2, NACT, lgts, NP2, HID);

  sample_k<<<BATCH, 128, 0, stream>>>(lgts, idxR, lenR, idxS, lenS, out);
}

// Round 3
// 215.353 us; speedup vs baseline: 1.1113x; 1.0256x over previous
//
#include <hip/hip_runtime.h>
#include <cstdint>
#include <cstddef>

#define BATCH 8192
#define DIN   1025
#define HID   1024
#define NACT  1026
#define NHEAD 513
#define KSEL  32
#define KP0   1088   /* DIN padded to multiple of 64 */
#define NP2   1152   /* NACT padded to multiple of 128 */

typedef unsigned short u16;
typedef short bf16x8 __attribute__((ext_vector_type(8)));
typedef float f32x4 __attribute__((ext_vector_type(4)));

__device__ __forceinline__ u16 f2bf(float f) {
  unsigned u = __float_as_uint(f);
  u += 0x7fff + ((u >> 16) & 1);   // round-to-nearest-even
  return (u16)(u >> 16);
}
__device__ __forceinline__ float bf2f(u16 h) {
  return __uint_as_float((unsigned)h << 16);
}

__device__ __forceinline__ void async_cp16(const u16* g, u16* l) {
  __builtin_amdgcn_global_load_lds((const __attribute__((address_space(1))) void*)g,
                                   (__attribute__((address_space(3))) void*)l,
                                   16, 0, 0);
}

// ---------------- conversion kernels ----------------

// state f32 [BATCH][DIN] -> bf16 [BATCH][KP0], zero-padded K. 4 elems/thread.
__global__ void cvt_state(const float* __restrict__ in, u16* __restrict__ out) {
  int idx = blockIdx.x * 256 + threadIdx.x;           // one idx = 4 output elems
  const int QPR = KP0 / 4;                            // 272 quads per row
  if (idx >= BATCH * QPR) return;
  int r  = idx / QPR;
  int c4 = (idx - r * QPR) * 4;
  const float* src = in + (size_t)r * DIN + c4;
  ushort4 o;
  if (c4 + 3 < DIN) {
    o.x = f2bf(src[0]); o.y = f2bf(src[1]); o.z = f2bf(src[2]); o.w = f2bf(src[3]);
  } else {
    o.x = (c4 + 0 < DIN) ? f2bf(src[0]) : 0;
    o.y = (c4 + 1 < DIN) ? f2bf(src[1]) : 0;
    o.z = (c4 + 2 < DIN) ? f2bf(src[2]) : 0;
    o.w = (c4 + 3 < DIN) ? f2bf(src[3]) : 0;
  }
  *(ushort4*)(out + (size_t)r * KP0 + c4) = o;
}

// All three weight matrices: f32 [K][N] -> bf16 [Np][Kp] transposed+padded.
__global__ void cvt_w_all(const float* __restrict__ W0, const float* __restrict__ W1,
                          const float* __restrict__ W2,
                          u16* __restrict__ W0t, u16* __restrict__ W1t,
                          u16* __restrict__ W2t) {
  const float* W; u16* Wt; int K, N, Kp, Np;
  if (blockIdx.z == 0)      { W = W0; Wt = W0t; K = DIN; N = HID;  Kp = KP0; Np = HID; }
  else if (blockIdx.z == 1) { W = W1; Wt = W1t; K = HID; N = HID;  Kp = HID; Np = HID; }
  else                      { W = W2; Wt = W2t; K = HID; N = NACT; Kp = HID; Np = NP2; }
  int k0 = blockIdx.y * 32, n0 = blockIdx.x * 32;
  if (k0 >= Kp || n0 >= Np) return;
  __shared__ float tile[32][33];
  int tx = threadIdx.x, ty = threadIdx.y;
#pragma unroll
  for (int i = 0; i < 32; i += 8) {
    int k = k0 + ty + i, n = n0 + tx;
    tile[ty + i][tx] = (k < K && n < N) ? W[(size_t)k * N + n] : 0.f;
  }
  __syncthreads();
#pragma unroll
  for (int i = 0; i < 32; i += 8) {
    int n = n0 + ty + i, k = k0 + tx;
    if (n < Np && k < Kp) Wt[(size_t)n * Kp + k] = f2bf(tile[tx][ty + i]);
  }
}

// ---------------- GEMM: C[M][ldc] = A[M][K] * Bt[N][K]^T (+bias, relu) ----------------
// tile 64x128 (MxN), BK=64, 4 waves each 32x64 (2x4 MFMA 16x16x32 tiles).
// grid = (N/128, M/64) -> 1024+ blocks = 4 blocks/CU (16 waves/CU) for latency hiding.
// LDS: ldsA[64][64] | ldsB[128][64] bf16 = 24 KB. XOR kquad<->row swizzle keeps
// the fragment ds_read_b128s at the bank floor while global_load_lds dst stays
// lane-contiguous (wave-uniform base + lane*16B HW rule).

template<bool RELU, bool OBF16>
__global__ __launch_bounds__(256, 4)
void gemm_bt(const u16* __restrict__ A, const u16* __restrict__ Bt,
             const float* __restrict__ bias, int nbias,
             void* __restrict__ Cout, int ldc, int K)
{
  __shared__ __align__(16) u16 lds[12288];   // 24 KB
  u16* ldsA = lds;           // 4096 u16
  u16* ldsB = lds + 4096;    // 8192 u16

  const int tid   = threadIdx.x;
  const int wave  = tid >> 6;
  const int lane  = tid & 63;
  const int waveM = wave >> 1, waveN = wave & 1;
  const int lr = lane & 15, lq = lane >> 4;
  const size_t bm = (size_t)blockIdx.y * 64;
  const size_t bn = (size_t)blockIdx.x * 128;

  // staging: chunk c (16B) -> row c>>3, slot c&7, global kquad g = (c&7)^(row&7)
  const int cw  = wave * 64 + lane;          // 0..255
  const int row = cw >> 3;                   // 0..31
  const int g   = (cw & 7) ^ (row & 7);
  const u16* gA0 = A  + (bm + row) * K + g * 8;   // + j*32 rows, j=0..1
  const u16* gB0 = Bt + (bn + row) * K + g * 8;   // + j*32 rows, j=0..3
  u16* lA0 = ldsA + wave * 512;                   // wave-uniform; HW adds lane*16B
  u16* lB0 = ldsB + wave * 512;

  f32x4 acc[2][4] = {};

  // fragment: element (row, kk*32 + lq*8) at slot s = (lq + kk*4) ^ (row&7)
  const int r7 = lr & 7;
  const int s0 = lq ^ r7;
  const int s1 = (lq + 4) ^ r7;
  const u16* pa = ldsA + (waveM * 32 + lr) * 64;
  const u16* pb = ldsB + (waveN * 64 + lr) * 64;

  for (int k0 = 0; k0 < K; k0 += 64) {
#pragma unroll
    for (int j = 0; j < 2; ++j)
      async_cp16(gA0 + j * 32 * (size_t)K + k0, lA0 + j * 2048);
#pragma unroll
    for (int j = 0; j < 4; ++j)
      async_cp16(gB0 + j * 32 * (size_t)K + k0, lB0 + j * 2048);
    __syncthreads();

#pragma unroll
    for (int kk = 0; kk < 2; ++kk) {
      const int s = kk ? s1 : s0;
      bf16x8 af[2], bf[4];
#pragma unroll
      for (int t = 0; t < 2; ++t) af[t] = *(const bf16x8*)(pa + t * 1024 + s * 8);
#pragma unroll
      for (int t = 0; t < 4; ++t) bf[t] = *(const bf16x8*)(pb + t * 1024 + s * 8);
#pragma unroll
      for (int tm = 0; tm < 2; ++tm)
#pragma unroll
        for (int tn = 0; tn < 4; ++tn)
          acc[tm][tn] = __builtin_amdgcn_mfma_f32_16x16x32_bf16(af[tm], bf[tn], acc[tm][tn], 0, 0, 0);
    }
    __syncthreads();
  }

  // epilogue: D row = lq*4 + r, col = lr (m89-verified layout)
#pragma unroll
  for (int tm = 0; tm < 2; ++tm) {
    size_t rw = bm + waveM * 32 + tm * 16 + lq * 4;
#pragma unroll
    for (int tn = 0; tn < 4; ++tn) {
      int col = (int)bn + waveN * 64 + tn * 16 + lr;
      float bv = (col < nbias) ? bias[col] : 0.f;
#pragma unroll
      for (int r = 0; r < 4; ++r) {
        float v = acc[tm][tn][r] + bv;
        if (RELU) v = fmaxf(v, 0.f);
        if (OBF16) ((u16*)Cout)[(rw + r) * ldc + col] = f2bf(v);
        else       ((float*)Cout)[(rw + r) * ldc + col] = v;
      }
    }
  }
}

// ---------------- sampling without replacement ----------------
// one block (2 waves) per batch row: wave 0 -> group R, wave 1 -> group S.
// Incremental: e_i = exp(x_i - m); S = sum e; T = sum e*x.
// step t: logZ = m + log(S_t); ent += logZ - T_t/S_t; logp += x_idx - logZ;
// removals via exclusive lane prefix sums over the 32 steps.

__global__ void sample_k(const u16* __restrict__ logits,
                         const int* __restrict__ idxR, const int* __restrict__ lenR,
                         const int* __restrict__ idxS, const int* __restrict__ lenS,
                         float* __restrict__ out)
{
  const int row  = blockIdx.x;
  const int w    = threadIdx.x >> 6;
  const int lane = threadIdx.x & 63;
  const u16* x = logits + (size_t)row * NP2 + w * NHEAD;
  const int* sidx = (w ? idxS : idxR) + (size_t)row * KSEL;
  const int slen  = (w ? lenS : lenR)[row];

  float m = -3.4e38f;
  for (int i = lane; i < NHEAD; i += 64) m = fmaxf(m, bf2f(x[i]));
#pragma unroll
  for (int d = 32; d; d >>= 1) m = fmaxf(m, __shfl_xor(m, d, 64));

  float S = 0.f, T = 0.f;
  for (int i = lane; i < NHEAD; i += 64) {
    float xi = bf2f(x[i]);
    float e = __expf(xi - m);
    S += e; T += e * xi;
  }
#pragma unroll
  for (int d = 32; d; d >>= 1) { S += __shfl_xor(S, d, 64); T += __shfl_xor(T, d, 64); }

  float e = 0.f, ex = 0.f, xt = 0.f;
  int active = (lane < KSEL) && (lane < slen);
  int valid = 0;
  if (active) {
    int id = sidx[lane];
    if (id >= 0) {
      valid = 1;
      xt = bf2f(x[id]);
      e  = __expf(xt - m);
      ex = e * xt;
    }
  }
  float pe = e, pex = ex;
#pragma unroll
  for (int d = 1; d < 32; d <<= 1) {
    float a = __shfl_up(pe, d, 64);
    float b = __shfl_up(pex, d, 64);
    if (lane >= d) { pe += a; pex += b; }
  }
  float lp = 0.f, en = 0.f;
  if (active) {
    float St = S - (pe - e);
    float Tt = T - (pex - ex);
    float logZ = m + __logf(St);
    en = logZ - Tt / St;
    if (valid) lp = xt - logZ;
  }
#pragma unroll
  for (int d = 32; d; d >>= 1) { lp += __shfl_xor(lp, d, 64); en += __shfl_xor(en, d, 64); }

  __shared__ float sh[4];
  if (lane == 0) { sh[w * 2] = lp; sh[w * 2 + 1] = en; }
  __syncthreads();
  if (threadIdx.x == 0) {
    out[row]         = sh[0] + sh[2];
    out[BATCH + row] = sh[1] + sh[3];
  }
}

// ---------------- launch ----------------

extern "C" void kernel_launch(void* const* d_in, const int* in_sizes, int n_in,
                              void* d_out, int out_size, void* d_ws, size_t ws_size,
                              hipStream_t stream) {
  (void)in_sizes; (void)n_in; (void)out_size; (void)ws_size;
  const float* state = (const float*)d_in[0];
  const float* W0 = (const float*)d_in[1];
  const float* b0 = (const float*)d_in[2];
  const float* W1 = (const float*)d_in[3];
  const float* b1 = (const float*)d_in[4];
  const float* W2 = (const float*)d_in[5];
  const float* b2 = (const float*)d_in[6];
  const int* idxR = (const int*)d_in[7];
  const int* lenR = (const int*)d_in[8];
  const int* idxS = (const int*)d_in[9];
  const int* lenS = (const int*)d_in[10];
  float* out = (float*)d_out;

  char* ws = (char*)d_ws;
  size_t off = 0;
  auto alloc = [&](size_t bytes) -> char* {
    char* p = ws + off;
    off = (off + bytes + 255) & ~(size_t)255;
    return p;
  };
  u16* As     = (u16*)alloc((size_t)BATCH * KP0 * 2);   // 17.8 MB
  u16* W0t    = (u16*)alloc((size_t)HID * KP0 * 2);     //  2.2 MB
  u16* W1t    = (u16*)alloc((size_t)HID * HID * 2);     //  2.1 MB
  u16* W2t    = (u16*)alloc((size_t)NP2 * HID * 2);     //  2.4 MB
  u16* h1     = (u16*)alloc((size_t)BATCH * HID * 2);   // 16.8 MB
  u16* lgts   = (u16*)alloc((size_t)BATCH * NP2 * 2);   // 18.9 MB
  u16* h2 = As;   // As is dead after GEMM1; reuse for h2

  cvt_state<<<(BATCH * (KP0 / 4) + 255) / 256, 256, 0, stream>>>(state, As);
  cvt_w_all<<<dim3(NP2 / 32, KP0 / 32, 3), dim3(32, 8), 0, stream>>>(W0, W1, W2, W0t, W1t, W2t);

  gemm_bt<true,  true><<<dim3(HID / 128, BATCH / 64), 256, 0, stream>>>(As, W0t, b0, HID,  h1,   HID, KP0);
  gemm_bt<true,  true><<<dim3(HID / 128, BATCH / 64), 256, 0, stream>>>(h1, W1t, b1, HID,  h2,   HID, HID);
  gemm_bt<false, true><<<dim3(NP2 / 128, BATCH / 64), 256, 0, stream>>>(h2, W2t, b2, NACT, lgts, NP2, HID);

  sample_k<<<BATCH, 128, 0, stream>>>(lgts, idxR, lenR, idxS, lenS, out);
}

// Round 4
// 206.146 us; speedup vs baseline: 1.1609x; 1.0447x over previous
//
#include <hip/hip_runtime.h>
#include <cstdint>
#include <cstddef>

#define BATCH 8192
#define DIN   1025
#define HID   1024
#define NACT  1026
#define NHEAD 513
#define KSEL  32
#define KP0   1088   /* DIN padded to multiple of 64 */
#define NP2   1152   /* NACT padded to multiple of 128 */

typedef unsigned short u16;
typedef short bf16x8 __attribute__((ext_vector_type(8)));
typedef float f32x4 __attribute__((ext_vector_type(4)));

__device__ __forceinline__ u16 f2bf(float f) {
  unsigned u = __float_as_uint(f);
  u += 0x7fff + ((u >> 16) & 1);   // round-to-nearest-even
  return (u16)(u >> 16);
}
__device__ __forceinline__ float bf2f(u16 h) {
  return __uint_as_float((unsigned)h << 16);
}

__device__ __forceinline__ void async_cp16(const u16* g, u16* l) {
  __builtin_amdgcn_global_load_lds((const __attribute__((address_space(1))) void*)g,
                                   (__attribute__((address_space(3))) void*)l,
                                   16, 0, 0);
}

// ---------------- conversion kernels ----------------

// state f32 [BATCH][DIN] -> bf16 [BATCH][KP0], zero-padded K. 4 elems/thread.
__global__ void cvt_state(const float* __restrict__ in, u16* __restrict__ out) {
  int idx = blockIdx.x * 256 + threadIdx.x;           // one idx = 4 output elems
  const int QPR = KP0 / 4;                            // 272 quads per row
  if (idx >= BATCH * QPR) return;
  int r  = idx / QPR;
  int c4 = (idx - r * QPR) * 4;
  const float* src = in + (size_t)r * DIN + c4;
  ushort4 o;
  if (c4 + 3 < DIN) {
    o.x = f2bf(src[0]); o.y = f2bf(src[1]); o.z = f2bf(src[2]); o.w = f2bf(src[3]);
  } else {
    o.x = (c4 + 0 < DIN) ? f2bf(src[0]) : 0;
    o.y = (c4 + 1 < DIN) ? f2bf(src[1]) : 0;
    o.z = (c4 + 2 < DIN) ? f2bf(src[2]) : 0;
    o.w = (c4 + 3 < DIN) ? f2bf(src[3]) : 0;
  }
  *(ushort4*)(out + (size_t)r * KP0 + c4) = o;
}

// All three weight matrices: f32 [K][N] -> bf16 [Np][Kp] transposed+padded.
__global__ void cvt_w_all(const float* __restrict__ W0, const float* __restrict__ W1,
                          const float* __restrict__ W2,
                          u16* __restrict__ W0t, u16* __restrict__ W1t,
                          u16* __restrict__ W2t) {
  const float* W; u16* Wt; int K, N, Kp, Np;
  if (blockIdx.z == 0)      { W = W0; Wt = W0t; K = DIN; N = HID;  Kp = KP0; Np = HID; }
  else if (blockIdx.z == 1) { W = W1; Wt = W1t; K = HID; N = HID;  Kp = HID; Np = HID; }
  else                      { W = W2; Wt = W2t; K = HID; N = NACT; Kp = HID; Np = NP2; }
  int k0 = blockIdx.y * 32, n0 = blockIdx.x * 32;
  if (k0 >= Kp || n0 >= Np) return;
  __shared__ float tile[32][33];
  int tx = threadIdx.x, ty = threadIdx.y;
#pragma unroll
  for (int i = 0; i < 32; i += 8) {
    int k = k0 + ty + i, n = n0 + tx;
    tile[ty + i][tx] = (k < K && n < N) ? W[(size_t)k * N + n] : 0.f;
  }
  __syncthreads();
#pragma unroll
  for (int i = 0; i < 32; i += 8) {
    int n = n0 + ty + i, k = k0 + tx;
    if (n < Np && k < Kp) Wt[(size_t)n * Kp + k] = f2bf(tile[tx][ty + i]);
  }
}

// ---------------- GEMM: C[M][ldc] = A[M][K] * Bt[N][K]^T (+bias, relu) ----------------
// tile 64x128 (MxN), BK=64, 4 waves each 32x64 (2x4 MFMA 16x16x32 tiles).
// 1D grid with XCD-aware swizzle: all NT n-tiles of one m-tile get dispatch ids
// congruent mod 8 -> same XCD (d%8 is the XCD round-robin) -> the A M-tile is
// HBM-fetched once per XCD, remaining 7 readers hit that XCD's L2. B panel
// (~2.2 MB) becomes L2-resident per XCD. Cuts the per-iter barrier drain from
// HBM-latency (~900cyc) to L2-latency (~200cyc) class.

template<bool RELU, bool OBF16, int NT>
__global__ __launch_bounds__(256, 4)
void gemm_bt(const u16* __restrict__ A, const u16* __restrict__ Bt,
             const float* __restrict__ bias, int nbias,
             void* __restrict__ Cout, int ldc, int K)
{
  __shared__ __align__(16) u16 lds[12288];   // 24 KB
  u16* ldsA = lds;           // 4096 u16
  u16* ldsB = lds + 4096;    // 8192 u16

  // XCD swizzle: d = group*(8*NT) + n*8 + m8 ; m = group*8 + m8
  const int d     = blockIdx.x;
  const int group = d / (8 * NT);
  const int rsub  = d - group * (8 * NT);
  const int ntile = rsub >> 3;
  const int mtile = group * 8 + (rsub & 7);

  const int tid   = threadIdx.x;
  const int wave  = tid >> 6;
  const int lane  = tid & 63;
  const int waveM = wave >> 1, waveN = wave & 1;
  const int lr = lane & 15, lq = lane >> 4;
  const size_t bm = (size_t)mtile * 64;
  const size_t bn = (size_t)ntile * 128;

  // staging: chunk c (16B) -> row c>>3, slot c&7, global kquad g = (c&7)^(row&7)
  const int cw  = wave * 64 + lane;          // 0..255
  const int row = cw >> 3;                   // 0..31
  const int g   = (cw & 7) ^ (row & 7);
  const u16* gA0 = A  + (bm + row) * K + g * 8;   // + j*32 rows, j=0..1
  const u16* gB0 = Bt + (bn + row) * K + g * 8;   // + j*32 rows, j=0..3
  u16* lA0 = ldsA + wave * 512;                   // wave-uniform; HW adds lane*16B
  u16* lB0 = ldsB + wave * 512;

  f32x4 acc[2][4] = {};

  // fragment: element (row, kk*32 + lq*8) at slot s = (lq + kk*4) ^ (row&7)
  const int r7 = lr & 7;
  const int s0 = lq ^ r7;
  const int s1 = (lq + 4) ^ r7;
  const u16* pa = ldsA + (waveM * 32 + lr) * 64;
  const u16* pb = ldsB + (waveN * 64 + lr) * 64;

  for (int k0 = 0; k0 < K; k0 += 64) {
#pragma unroll
    for (int j = 0; j < 2; ++j)
      async_cp16(gA0 + j * 32 * (size_t)K + k0, lA0 + j * 2048);
#pragma unroll
    for (int j = 0; j < 4; ++j)
      async_cp16(gB0 + j * 32 * (size_t)K + k0, lB0 + j * 2048);
    __syncthreads();

#pragma unroll
    for (int kk = 0; kk < 2; ++kk) {
      const int s = kk ? s1 : s0;
      bf16x8 af[2], bf[4];
#pragma unroll
      for (int t = 0; t < 2; ++t) af[t] = *(const bf16x8*)(pa + t * 1024 + s * 8);
#pragma unroll
      for (int t = 0; t < 4; ++t) bf[t] = *(const bf16x8*)(pb + t * 1024 + s * 8);
#pragma unroll
      for (int tm = 0; tm < 2; ++tm)
#pragma unroll
        for (int tn = 0; tn < 4; ++tn)
          acc[tm][tn] = __builtin_amdgcn_mfma_f32_16x16x32_bf16(af[tm], bf[tn], acc[tm][tn], 0, 0, 0);
    }
    __syncthreads();
  }

  // epilogue: D row = lq*4 + r, col = lr (m89-verified layout)
#pragma unroll
  for (int tm = 0; tm < 2; ++tm) {
    size_t rw = bm + waveM * 32 + tm * 16 + lq * 4;
#pragma unroll
    for (int tn = 0; tn < 4; ++tn) {
      int col = (int)bn + waveN * 64 + tn * 16 + lr;
      float bv = (col < nbias) ? bias[col] : 0.f;
#pragma unroll
      for (int r = 0; r < 4; ++r) {
        float v = acc[tm][tn][r] + bv;
        if (RELU) v = fmaxf(v, 0.f);
        if (OBF16) ((u16*)Cout)[(rw + r) * ldc + col] = f2bf(v);
        else       ((float*)Cout)[(rw + r) * ldc + col] = v;
      }
    }
  }
}

// ---------------- sampling without replacement ----------------
// one block (2 waves) per batch row: wave 0 -> group R, wave 1 -> group S.
// Incremental: e_i = exp(x_i - m); S = sum e; T = sum e*x.
// step t: logZ = m + log(S_t); ent += logZ - T_t/S_t; logp += x_idx - logZ;
// removals via exclusive lane prefix sums over the 32 steps.

__global__ void sample_k(const u16* __restrict__ logits,
                         const int* __restrict__ idxR, const int* __restrict__ lenR,
                         const int* __restrict__ idxS, const int* __restrict__ lenS,
                         float* __restrict__ out)
{
  const int row  = blockIdx.x;
  const int w    = threadIdx.x >> 6;
  const int lane = threadIdx.x & 63;
  const u16* x = logits + (size_t)row * NP2 + w * NHEAD;
  const int* sidx = (w ? idxS : idxR) + (size_t)row * KSEL;
  const int slen  = (w ? lenS : lenR)[row];

  float m = -3.4e38f;
  for (int i = lane; i < NHEAD; i += 64) m = fmaxf(m, bf2f(x[i]));
#pragma unroll
  for (int d = 32; d; d >>= 1) m = fmaxf(m, __shfl_xor(m, d, 64));

  float S = 0.f, T = 0.f;
  for (int i = lane; i < NHEAD; i += 64) {
    float xi = bf2f(x[i]);
    float e = __expf(xi - m);
    S += e; T += e * xi;
  }
#pragma unroll
  for (int d = 32; d; d >>= 1) { S += __shfl_xor(S, d, 64); T += __shfl_xor(T, d, 64); }

  float e = 0.f, ex = 0.f, xt = 0.f;
  int active = (lane < KSEL) && (lane < slen);
  int valid = 0;
  if (active) {
    int id = sidx[lane];
    if (id >= 0) {
      valid = 1;
      xt = bf2f(x[id]);
      e  = __expf(xt - m);
      ex = e * xt;
    }
  }
  float pe = e, pex = ex;
#pragma unroll
  for (int d = 1; d < 32; d <<= 1) {
    float a = __shfl_up(pe, d, 64);
    float b = __shfl_up(pex, d, 64);
    if (lane >= d) { pe += a; pex += b; }
  }
  float lp = 0.f, en = 0.f;
  if (active) {
    float St = S - (pe - e);
    float Tt = T - (pex - ex);
    float logZ = m + __logf(St);
    en = logZ - Tt / St;
    if (valid) lp = xt - logZ;
  }
#pragma unroll
  for (int d = 32; d; d >>= 1) { lp += __shfl_xor(lp, d, 64); en += __shfl_xor(en, d, 64); }

  __shared__ float sh[4];
  if (lane == 0) { sh[w * 2] = lp; sh[w * 2 + 1] = en; }
  __syncthreads();
  if (threadIdx.x == 0) {
    out[row]         = sh[0] + sh[2];
    out[BATCH + row] = sh[1] + sh[3];
  }
}

// ---------------- launch ----------------

extern "C" void kernel_launch(void* const* d_in, const int* in_sizes, int n_in,
                              void* d_out, int out_size, void* d_ws, size_t ws_size,
                              hipStream_t stream) {
  (void)in_sizes; (void)n_in; (void)out_size; (void)ws_size;
  const float* state = (const float*)d_in[0];
  const float* W0 = (const float*)d_in[1];
  const float* b0 = (const float*)d_in[2];
  const float* W1 = (const float*)d_in[3];
  const float* b1 = (const float*)d_in[4];
  const float* W2 = (const float*)d_in[5];
  const float* b2 = (const float*)d_in[6];
  const int* idxR = (const int*)d_in[7];
  const int* lenR = (const int*)d_in[8];
  const int* idxS = (const int*)d_in[9];
  const int* lenS = (const int*)d_in[10];
  float* out = (float*)d_out;

  char* ws = (char*)d_ws;
  size_t off = 0;
  auto alloc = [&](size_t bytes) -> char* {
    char* p = ws + off;
    off = (off + bytes + 255) & ~(size_t)255;
    return p;
  };
  u16* As     = (u16*)alloc((size_t)BATCH * KP0 * 2);   // 17.8 MB
  u16* W0t    = (u16*)alloc((size_t)HID * KP0 * 2);     //  2.2 MB
  u16* W1t    = (u16*)alloc((size_t)HID * HID * 2);     //  2.1 MB
  u16* W2t    = (u16*)alloc((size_t)NP2 * HID * 2);     //  2.4 MB
  u16* h1     = (u16*)alloc((size_t)BATCH * HID * 2);   // 16.8 MB
  u16* lgts   = (u16*)alloc((size_t)BATCH * NP2 * 2);   // 18.9 MB
  u16* h2 = As;   // As is dead after GEMM1; reuse for h2

  cvt_state<<<(BATCH * (KP0 / 4) + 255) / 256, 256, 0, stream>>>(state, As);
  cvt_w_all<<<dim3(NP2 / 32, KP0 / 32, 3), dim3(32, 8), 0, stream>>>(W0, W1, W2, W0t, W1t, W2t);

  gemm_bt<true,  true, 8><<<(BATCH / 64) * (HID / 128), 256, 0, stream>>>(As, W0t, b0, HID,  h1,   HID, KP0);
  gemm_bt<true,  true, 8><<<(BATCH / 64) * (HID / 128), 256, 0, stream>>>(h1, W1t, b1, HID,  h2,   HID, HID);
  gemm_bt<false, true, 9><<<(BATCH / 64) * (NP2 / 128), 256, 0, stream>>>(h2, W2t, b2, NACT, lgts, NP2, HID);

  sample_k<<<BATCH, 128, 0, stream>>>(lgts, idxR, lenR, idxS, lenS, out);
}